// Round 6
// baseline (2344.511 us; speedup 1.0000x reference)
//
#include <hip/hip_runtime.h>

// ---------------- constants ----------------
#define CUTOFF_F     0.35f
#define PI_F         3.14159265358979323846f
#define SQRT3_F      1.7320508075688772f
#define INV_SQRT3_F  0.5773502691896258f
#define INV_SQRT_S_F 0.17677669529663687f   // 1/sqrt(32)
#define INV_SQRT_V_F 0.25f                  // 1/sqrt(16)
#define A_SC_F       0.14433756729740643f   // 1/sqrt(48)

// ws layout (floats): [0..12) M matrix, [16..) node state double buffers
#define OFF_M    0
#define OFF_NODE 16

// M[c][k] = (1/256) * Y[:,c] . dirs[:,k];  Y = [1, sqrt3*dirs]
__global__ void mmat_kernel(const float* __restrict__ dirs, float* __restrict__ wf) {
  int t = threadIdx.x;
  if (t >= 12) return;
  int c = t / 3, k = t - c * 3;
  float acc = 0.f;
  for (int p = 0; p < 256; ++p) {
    float dk = dirs[p * 3 + k];
    acc += (c == 0) ? dk : dirs[p * 3 + (c - 1)] * dk;
  }
  wf[OFF_M + t] = acc * ((c == 0) ? (1.0f / 256.0f) : (SQRT3_F / 256.0f));
}

// s0[n][w] = (x[n,0:3] @ Wins)[w]/sqrt3 ; v0[n][u][k] = x[n,3+k]*Winv[u]
__global__ __launch_bounds__(256) void node_init_kernel(
    const float* __restrict__ x, const float* __restrict__ wins,
    const float* __restrict__ winv,
    float* __restrict__ s0, float* __restrict__ v0, int N)
{
  int t = blockIdx.x * 256 + threadIdx.x;
  int n = t / 80; int slot = t - n * 80;
  if (n >= N) return;
  if (slot < 32) {
    float acc = 0.f;
    #pragma unroll
    for (int d = 0; d < 3; ++d) acc += x[n * 6 + d] * wins[d * 32 + slot];
    s0[n * 32 + slot] = acc * INV_SQRT3_F;
  } else {
    int j = slot - 32; int u = j / 3; int k = j - u * 3;
    v0[n * 48 + j] = x[n * 6 + 3 + k] * winv[u];
  }
}

// self-connection: sn = (sc @ Wsc_s)*inv_s ; vn = (vc x Wsc_v)*inv_v  (full overwrite)
__global__ __launch_bounds__(256) void selfmix_kernel(
    const float* __restrict__ sc, const float* __restrict__ vc,
    float* __restrict__ sn, float* __restrict__ vn,
    const float* __restrict__ wscs, const float* __restrict__ wscv,
    int layer, int N)
{
  int t = blockIdx.x * 256 + threadIdx.x;
  int n = t / 80; int slot = t - n * 80;
  if (n >= N) return;
  if (slot < 32) {
    const float* W = wscs + layer * 1024;
    float acc = 0.f;
    #pragma unroll
    for (int u = 0; u < 32; ++u) acc += sc[n * 32 + u] * W[u * 32 + slot];
    sn[n * 32 + slot] = acc * INV_SQRT_S_F;
  } else {
    int j = slot - 32; int w = j / 3; int k = j - w * 3;
    const float* W = wscv + layer * 256;
    float acc = 0.f;
    #pragma unroll
    for (int u = 0; u < 16; ++u) acc += vc[n * 48 + u * 3 + k] * W[u * 16 + w];
    vn[n * 48 + j] = acc * INV_SQRT_V_F;
  }
}

// ---------------- per-edge kernel: 4 waves per 64 edges, w-split ----------------
// lane = edge-in-block; wave q owns output-column quarter:
//   A,B: w in [8q,8q+8)   C, D: w in [4q,4q+4)
// Each wave writes EXCLUSIVE LDS slots -> no LDS atomics, 4 barriers.
// sAcc slots per edge: A 0..31 | B 32..63 | C 64..79 | D 80..127 (stride 129).
// After pg phase the same slots hold gates: gs 0..31 | gv 32..79.
__global__ __launch_bounds__(256, 3) void edge_kernel(
    const int* __restrict__ ei, const float* __restrict__ ed,
    const float* __restrict__ esh,
    const float* __restrict__ sc, const float* __restrict__ vc,
    float* __restrict__ sn, float* __restrict__ vn,
    const float* __restrict__ wr1, const float* __restrict__ br1,
    const float* __restrict__ wr2, const float* __restrict__ br2,
    const float* __restrict__ wpgs, const float* __restrict__ wpgv,
    const float* __restrict__ wlos, const float* __restrict__ wlov,
    int layer, int E, int N)
{
  __shared__ float sH[64 * 33];     // hext (stride 33 -> conflict-free)
  __shared__ float sAcc[64 * 129];  // stride 129 -> conflict-free

  const int tid  = threadIdx.x;
  const int lane = tid & 63;
  const int q    = tid >> 6;        // wave id 0..3
  const int wq8  = q * 8;
  const int wq4  = q * 4;
  const int e    = blockIdx.x * 64 + lane;
  const bool valid = e < E;
  const int eL   = valid ? e : (E - 1);
  int srcn = ei[eL];     srcn = (srcn < 0) ? 0 : (srcn >= N ? N - 1 : srcn);
  int dstn = ei[E + eL]; dstn = (dstn < 0) ? 0 : (dstn >= N ? N - 1 : dstn);
  const float y0  = esh[eL * 4 + 0];
  const float y1x = esh[eL * 4 + 1];
  const float y1y = esh[eL * 4 + 2];
  const float y1z = esh[eL * 4 + 3];

  // ---- h: wave q computes h[8q..8q+8); wave 0 adds bias row h[32]=1 ----
  {
    const float d = ed[eL];
    const float inv_w = 12.0f / CUTOFF_F;
    float cut = (d < CUTOFF_F) ? 0.5f * (__cosf(d * (PI_F / CUTOFF_F)) + 1.0f) : 0.0f;
    float rb[6];
    #pragma unroll
    for (int r = 0; r < 6; ++r) {
      float z = (d - 0.07f * (float)r) * inv_w;
      rb[r] = __expf(-0.5f * z * z) * cut;
    }
    const float* W1p = wr1 + layer * 192;
    const float* B1p = br1 + layer * 32;
    #pragma unroll
    for (int jj = 0; jj < 8; ++jj) {
      const int j = wq8 + jj;
      float z = B1p[j];
      #pragma unroll
      for (int r = 0; r < 6; ++r) z += rb[r] * W1p[r * 32 + j];
      sH[lane * 33 + j] = z / (1.0f + __expf(-z));   // silu
    }
    if (q == 0) sH[lane * 33 + 32] = 1.0f;
  }

  // ---- left operands (vectorized loads) ----
  float sj[32];
  { const float4* sp = (const float4*)(sc + (size_t)srcn * 32);
    #pragma unroll
    for (int m = 0; m < 8; ++m) { float4 t4 = sp[m];
      sj[m*4] = t4.x; sj[m*4+1] = t4.y; sj[m*4+2] = t4.z; sj[m*4+3] = t4.w; } }
  float vj[48];
  { const float4* vp = (const float4*)(vc + (size_t)srcn * 48);
    #pragma unroll
    for (int m = 0; m < 12; ++m) { float4 t4 = vp[m];
      vj[m*4] = t4.x; vj[m*4+1] = t4.y; vj[m*4+2] = t4.z; vj[m*4+3] = t4.w; } }
  float vdot[16];
  #pragma unroll
  for (int u = 0; u < 16; ++u)
    vdot[u] = vj[u*3] * y1x + vj[u*3+1] * y1y + vj[u*3+2] * y1z;

  __syncthreads();  // h ready

  // ---- ABCD contraction over all 33 c-rows, w-quarter per wave ----
  float A[8], B[8], C[4], D[12];
  #pragma unroll
  for (int i = 0; i < 8; ++i) { A[i] = 0.f; B[i] = 0.f; }
  #pragma unroll
  for (int i = 0; i < 4; ++i) C[i] = 0.f;
  #pragma unroll
  for (int i = 0; i < 12; ++i) D[i] = 0.f;

  for (int c = 0; c < 33; ++c) {
    const float hc = sH[lane * 33 + c];
    const float* row = (c < 32) ? (wr2 + (size_t)(layer * 32 + c) * 2304)
                                : (br2 + (size_t)layer * 2304);
    const float* w1 = row + wq8;            // W1: u*32 + w
    const float* w2 = row + 1024 + wq8;     // W2: u*32 + w
    const float* w3 = row + 1536 + wq4;     // W3: u*16 + w
    const float* w4 = row + 2048 + wq4;     // W4: u*16 + w
    #pragma unroll
    for (int u = 0; u < 32; ++u) {
      const float p = hc * sj[u];
      #pragma unroll
      for (int wi = 0; wi < 8; ++wi) A[wi] += p * w1[u * 32 + wi];
      #pragma unroll
      for (int wi = 0; wi < 4; ++wi) C[wi] += p * w3[u * 16 + wi];
    }
    #pragma unroll
    for (int u = 0; u < 16; ++u) {
      const float pb = hc * vdot[u];
      #pragma unroll
      for (int wi = 0; wi < 8; ++wi) B[wi] += pb * w2[u * 32 + wi];
      const float a0 = hc * vj[u * 3 + 0];
      const float a1 = hc * vj[u * 3 + 1];
      const float a2 = hc * vj[u * 3 + 2];
      #pragma unroll
      for (int wi = 0; wi < 4; ++wi) {
        const float t = w4[u * 16 + wi];
        D[wi * 3 + 0] += a0 * t;
        D[wi * 3 + 1] += a1 * t;
        D[wi * 3 + 2] += a2 * t;
      }
    }
  }

  // each wave writes its exclusive slots
  #pragma unroll
  for (int wi = 0; wi < 8; ++wi) sAcc[lane * 129 + wq8 + wi] = A[wi];
  #pragma unroll
  for (int wi = 0; wi < 8; ++wi) sAcc[lane * 129 + 32 + wq8 + wi] = B[wi];
  #pragma unroll
  for (int wi = 0; wi < 4; ++wi) sAcc[lane * 129 + 64 + wq4 + wi] = C[wi];
  #pragma unroll
  for (int j = 0; j < 12; ++j)  sAcc[lane * 129 + 80 + wq4 * 3 + j] = D[j];
  __syncthreads();  // full A..D visible

  // ---- pg phase (w-split, intra-wave gate groups) ----
  float ps[8], ps32[4];
  #pragma unroll
  for (int i = 0; i < 8; ++i) ps[i] = 0.f;
  #pragma unroll
  for (int i = 0; i < 4; ++i) ps32[i] = 0.f;
  {
    const float* Wp = wpgs + layer * 1536;
    #pragma unroll
    for (int u = 0; u < 32; ++u) {
      const float ms = A_SC_F * (y0 * sAcc[lane * 129 + u]
                               + INV_SQRT3_F * sAcc[lane * 129 + 32 + u]);
      #pragma unroll
      for (int jj = 0; jj < 8; ++jj) ps[jj]   += ms * Wp[u * 48 + wq8 + jj];
      #pragma unroll
      for (int wi = 0; wi < 4; ++wi) ps32[wi] += ms * Wp[u * 48 + 32 + wq4 + wi];
    }
  }
  float pv[12];
  #pragma unroll
  for (int i = 0; i < 12; ++i) pv[i] = 0.f;
  {
    const float* Wp = wpgv + layer * 256;
    #pragma unroll
    for (int u = 0; u < 16; ++u) {
      const float cu = sAcc[lane * 129 + 64 + u];
      const float m0 = A_SC_F * (cu * y1x + y0 * sAcc[lane * 129 + 80 + u * 3 + 0]);
      const float m1 = A_SC_F * (cu * y1y + y0 * sAcc[lane * 129 + 80 + u * 3 + 1]);
      const float m2 = A_SC_F * (cu * y1z + y0 * sAcc[lane * 129 + 80 + u * 3 + 2]);
      #pragma unroll
      for (int wi = 0; wi < 4; ++wi) {
        const float wv = Wp[u * 16 + wq4 + wi];
        pv[wi * 3 + 0] += m0 * wv;
        pv[wi * 3 + 1] += m1 * wv;
        pv[wi * 3 + 2] += m2 * wv;
      }
    }
  }
  __syncthreads();  // everyone done READING A..D; safe to overwrite with gates

  // gates into exclusive slots: gs 0..31, gv 32..79
  #pragma unroll
  for (int jj = 0; jj < 8; ++jj) {
    const float t = ps[jj] * INV_SQRT_S_F;
    sAcc[lane * 129 + wq8 + jj] = t / (1.0f + __expf(-t));       // silu
  }
  #pragma unroll
  for (int wi = 0; wi < 4; ++wi) {
    const float g = 1.0f / (1.0f + __expf(-ps32[wi] * INV_SQRT_S_F));  // sigmoid
    #pragma unroll
    for (int k = 0; k < 3; ++k)
      sAcc[lane * 129 + 32 + (wq4 + wi) * 3 + k] = g * pv[wi * 3 + k] * INV_SQRT_V_F;
  }
  __syncthreads();  // gates visible

  // ---- o = g @ Wlo (w-split), scatter with HW fp32 atomics ----
  float os[8];
  #pragma unroll
  for (int i = 0; i < 8; ++i) os[i] = 0.f;
  {
    const float* Wp = wlos + layer * 1024;
    #pragma unroll
    for (int u = 0; u < 32; ++u) {
      const float g = sAcc[lane * 129 + u];
      #pragma unroll
      for (int wi = 0; wi < 8; ++wi) os[wi] += g * Wp[u * 32 + wq8 + wi];
    }
  }
  float ov[12];
  #pragma unroll
  for (int i = 0; i < 12; ++i) ov[i] = 0.f;
  {
    const float* Wp = wlov + layer * 256;
    #pragma unroll
    for (int u = 0; u < 16; ++u) {
      const float g0 = sAcc[lane * 129 + 32 + u * 3 + 0];
      const float g1 = sAcc[lane * 129 + 32 + u * 3 + 1];
      const float g2 = sAcc[lane * 129 + 32 + u * 3 + 2];
      #pragma unroll
      for (int wi = 0; wi < 4; ++wi) {
        const float wv = Wp[u * 16 + wq4 + wi];
        ov[wi * 3 + 0] += g0 * wv;
        ov[wi * 3 + 1] += g1 * wv;
        ov[wi * 3 + 2] += g2 * wv;
      }
    }
  }
  if (valid) {
    float* sdst = sn + (size_t)dstn * 32 + wq8;
    #pragma unroll
    for (int wi = 0; wi < 8; ++wi) unsafeAtomicAdd(&sdst[wi], os[wi] * INV_SQRT_S_F);
    float* vdst = vn + (size_t)dstn * 48 + wq4 * 3;
    #pragma unroll
    for (int j = 0; j < 12; ++j) unsafeAtomicAdd(&vdst[j], ov[j] * INV_SQRT_V_F);
  }
}

// out[n,k] = coeffs[n] @ M  (rho @ dirs collapsed analytically) — FP32 OUTPUT
__global__ __launch_bounds__(256) void final_kernel(
    const float* __restrict__ s0, const float* __restrict__ v0,
    const float* __restrict__ wos, const float* __restrict__ wov,
    const float* __restrict__ wf, float* __restrict__ out, int N)
{
  int n = blockIdx.x * 256 + threadIdx.x;
  if (n >= N) return;
  float cs = 0.f;
  #pragma unroll
  for (int u = 0; u < 32; ++u) cs += s0[n * 32 + u] * wos[u];
  cs *= INV_SQRT_S_F;
  float cv0 = 0.f, cv1 = 0.f, cv2 = 0.f;
  #pragma unroll
  for (int u = 0; u < 16; ++u) {
    const float wv = wov[u];
    cv0 += v0[n * 48 + u * 3 + 0] * wv;
    cv1 += v0[n * 48 + u * 3 + 1] * wv;
    cv2 += v0[n * 48 + u * 3 + 2] * wv;
  }
  cv0 *= INV_SQRT_V_F; cv1 *= INV_SQRT_V_F; cv2 *= INV_SQRT_V_F;
  #pragma unroll
  for (int k = 0; k < 3; ++k) {
    out[n * 3 + k] = cs  * wf[OFF_M + k]
                   + cv0 * wf[OFF_M + 3 + k]
                   + cv1 * wf[OFF_M + 6 + k]
                   + cv2 * wf[OFF_M + 9 + k];
  }
}

extern "C" void kernel_launch(void* const* d_in, const int* in_sizes, int n_in,
                              void* d_out, int out_size, void* d_ws, size_t ws_size,
                              hipStream_t stream)
{
  (void)n_in; (void)out_size; (void)ws_size;
  const float* x    = (const float*)d_in[0];
  const int*   ei   = (const int*)d_in[1];
  const float* ed   = (const float*)d_in[2];
  const float* esh  = (const float*)d_in[3];
  const float* dirs = (const float*)d_in[4];
  const float* wins = (const float*)d_in[5];
  const float* winv = (const float*)d_in[6];
  const float* wscs = (const float*)d_in[7];
  const float* wscv = (const float*)d_in[8];
  const float* wr1  = (const float*)d_in[9];
  const float* br1  = (const float*)d_in[10];
  const float* wr2  = (const float*)d_in[11];
  const float* br2  = (const float*)d_in[12];
  const float* wpgs = (const float*)d_in[13];
  const float* wpgv = (const float*)d_in[14];
  const float* wlos = (const float*)d_in[15];
  const float* wlov = (const float*)d_in[16];
  const float* wos  = (const float*)d_in[17];
  const float* wov  = (const float*)d_in[18];

  const int N = in_sizes[0] / 6;
  const int E = in_sizes[1] / 2;

  float* wf = (float*)d_ws;
  float* s0 = wf + OFF_NODE;
  float* v0 = s0 + (size_t)N * 32;
  float* s1 = v0 + (size_t)N * 48;
  float* v1 = s1 + (size_t)N * 32;

  const int nodeBlocks = (N * 80 + 255) / 256;
  const int edgeBlocks = (E + 63) / 64;
  const int finBlocks  = (N + 255) / 256;

  mmat_kernel<<<1, 64, 0, stream>>>(dirs, wf);
  node_init_kernel<<<nodeBlocks, 256, 0, stream>>>(x, wins, winv, s0, v0, N);

  // layer 0: s0/v0 -> s1/v1
  selfmix_kernel<<<nodeBlocks, 256, 0, stream>>>(s0, v0, s1, v1, wscs, wscv, 0, N);
  edge_kernel<<<edgeBlocks, 256, 0, stream>>>(ei, ed, esh, s0, v0, s1, v1,
      wr1, br1, wr2, br2, wpgs, wpgv, wlos, wlov, 0, E, N);
  // layer 1: s1/v1 -> s0/v0
  selfmix_kernel<<<nodeBlocks, 256, 0, stream>>>(s1, v1, s0, v0, wscs, wscv, 1, N);
  edge_kernel<<<edgeBlocks, 256, 0, stream>>>(ei, ed, esh, s1, v1, s0, v0,
      wr1, br1, wr2, br2, wpgs, wpgv, wlos, wlov, 1, E, N);

  final_kernel<<<finBlocks, 256, 0, stream>>>(s0, v0, wos, wov, wf,
      (float*)d_out, N);
}

// Round 7
// 883.592 us; speedup vs baseline: 2.6534x; 2.6534x over previous
//
#include <hip/hip_runtime.h>

// ---------------- constants ----------------
#define CUTOFF_F     0.35f
#define PI_F         3.14159265358979323846f
#define SQRT3_F      1.7320508075688772f
#define INV_SQRT3_F  0.5773502691896258f
#define INV_SQRT_S_F 0.17677669529663687f   // 1/sqrt(32)
#define INV_SQRT_V_F 0.25f                  // 1/sqrt(16)
#define A_SC_F       0.14433756729740643f   // 1/sqrt(48)

// ws layout (floats): [0..12) M matrix, [16..) node state double buffers
#define OFF_M    0
#define OFF_NODE 16

// M[c][k] = (1/256) * Y[:,c] . dirs[:,k];  Y = [1, sqrt3*dirs]
__global__ void mmat_kernel(const float* __restrict__ dirs, float* __restrict__ wf) {
  int t = threadIdx.x;
  if (t >= 12) return;
  int c = t / 3, k = t - c * 3;
  float acc = 0.f;
  for (int p = 0; p < 256; ++p) {
    float dk = dirs[p * 3 + k];
    acc += (c == 0) ? dk : dirs[p * 3 + (c - 1)] * dk;
  }
  wf[OFF_M + t] = acc * ((c == 0) ? (1.0f / 256.0f) : (SQRT3_F / 256.0f));
}

// s0[n][w] = (x[n,0:3] @ Wins)[w]/sqrt3 ; v0[n][u][k] = x[n,3+k]*Winv[u]
__global__ __launch_bounds__(256) void node_init_kernel(
    const float* __restrict__ x, const float* __restrict__ wins,
    const float* __restrict__ winv,
    float* __restrict__ s0, float* __restrict__ v0, int N)
{
  int t = blockIdx.x * 256 + threadIdx.x;
  int n = t / 80; int slot = t - n * 80;
  if (n >= N) return;
  if (slot < 32) {
    float acc = 0.f;
    #pragma unroll
    for (int d = 0; d < 3; ++d) acc += x[n * 6 + d] * wins[d * 32 + slot];
    s0[n * 32 + slot] = acc * INV_SQRT3_F;
  } else {
    int j = slot - 32; int u = j / 3; int k = j - u * 3;
    v0[n * 48 + j] = x[n * 6 + 3 + k] * winv[u];
  }
}

// self-connection: sn = (sc @ Wsc_s)*inv_s ; vn = (vc x Wsc_v)*inv_v  (full overwrite)
__global__ __launch_bounds__(256) void selfmix_kernel(
    const float* __restrict__ sc, const float* __restrict__ vc,
    float* __restrict__ sn, float* __restrict__ vn,
    const float* __restrict__ wscs, const float* __restrict__ wscv,
    int layer, int N)
{
  int t = blockIdx.x * 256 + threadIdx.x;
  int n = t / 80; int slot = t - n * 80;
  if (n >= N) return;
  if (slot < 32) {
    const float* W = wscs + layer * 1024;
    float acc = 0.f;
    #pragma unroll
    for (int u = 0; u < 32; ++u) acc += sc[n * 32 + u] * W[u * 32 + slot];
    sn[n * 32 + slot] = acc * INV_SQRT_S_F;
  } else {
    int j = slot - 32; int w = j / 3; int k = j - w * 3;
    const float* W = wscv + layer * 256;
    float acc = 0.f;
    #pragma unroll
    for (int u = 0; u < 16; ++u) acc += vc[n * 48 + u * 3 + k] * W[u * 16 + w];
    vn[n * 48 + j] = acc * INV_SQRT_V_F;
  }
}

// ---------------- per-edge kernel: 4 waves / 64 edges, w-split, LDS weights ---
// Identical math+choreography to the validated round-6 kernel; the ONLY change:
// Wr2 rows are staged into LDS via coalesced float4 vector loads (L1/L2 path)
// instead of being streamed through the 16KB scalar K$ (the measured stall).
// K-loop weight reads are wave-uniform LDS broadcasts (conflict-free b128).
__global__ __launch_bounds__(256, 2) void edge_kernel(
    const int* __restrict__ ei, const float* __restrict__ ed,
    const float* __restrict__ esh,
    const float* __restrict__ sc, const float* __restrict__ vc,
    float* __restrict__ sn, float* __restrict__ vn,
    const float* __restrict__ wr1, const float* __restrict__ br1,
    const float* __restrict__ wr2, const float* __restrict__ br2,
    const float* __restrict__ wpgs, const float* __restrict__ wpgv,
    const float* __restrict__ wlos, const float* __restrict__ wlov,
    int layer, int E, int N)
{
  __shared__ float sW[4 * 2304];    // weight tile: 4 c-rows (36.9 KB)
  __shared__ float sH[64 * 33];     // hext (stride 33 -> conflict-free)
  __shared__ float sAcc[64 * 129];  // A 0..31 | B 32..63 | C 64..79 | D 80..127

  const int tid  = threadIdx.x;
  const int lane = tid & 63;
  const int q    = tid >> 6;        // wave id 0..3
  const int wq8  = q * 8;
  const int wq4  = q * 4;
  const int e    = blockIdx.x * 64 + lane;
  const bool valid = e < E;
  const int eL   = valid ? e : (E - 1);
  int srcn = ei[eL];     srcn = (srcn < 0) ? 0 : (srcn >= N ? N - 1 : srcn);
  int dstn = ei[E + eL]; dstn = (dstn < 0) ? 0 : (dstn >= N ? N - 1 : dstn);
  const float y0  = esh[eL * 4 + 0];
  const float y1x = esh[eL * 4 + 1];
  const float y1y = esh[eL * 4 + 2];
  const float y1z = esh[eL * 4 + 3];

  // ---- h: wave q computes h[8q..8q+8); wave 0 adds bias row h[32]=1 ----
  {
    const float d = ed[eL];
    const float inv_w = 12.0f / CUTOFF_F;
    float cut = (d < CUTOFF_F) ? 0.5f * (__cosf(d * (PI_F / CUTOFF_F)) + 1.0f) : 0.0f;
    float rb[6];
    #pragma unroll
    for (int r = 0; r < 6; ++r) {
      float z = (d - 0.07f * (float)r) * inv_w;
      rb[r] = __expf(-0.5f * z * z) * cut;
    }
    const float* W1p = wr1 + layer * 192;
    const float* B1p = br1 + layer * 32;
    #pragma unroll
    for (int jj = 0; jj < 8; ++jj) {
      const int j = wq8 + jj;
      float z = B1p[j];
      #pragma unroll
      for (int r = 0; r < 6; ++r) z += rb[r] * W1p[r * 32 + j];
      sH[lane * 33 + j] = z / (1.0f + __expf(-z));   // silu
    }
    if (q == 0) sH[lane * 33 + 32] = 1.0f;
  }

  // ---- left operands (vectorized loads, registers) ----
  float sj[32];
  { const float4* sp = (const float4*)(sc + (size_t)srcn * 32);
    #pragma unroll
    for (int m = 0; m < 8; ++m) { float4 t4 = sp[m];
      sj[m*4] = t4.x; sj[m*4+1] = t4.y; sj[m*4+2] = t4.z; sj[m*4+3] = t4.w; } }
  float vj[48];
  { const float4* vp = (const float4*)(vc + (size_t)srcn * 48);
    #pragma unroll
    for (int m = 0; m < 12; ++m) { float4 t4 = vp[m];
      vj[m*4] = t4.x; vj[m*4+1] = t4.y; vj[m*4+2] = t4.z; vj[m*4+3] = t4.w; } }
  float vdot[16];
  #pragma unroll
  for (int u = 0; u < 16; ++u)
    vdot[u] = vj[u*3] * y1x + vj[u*3+1] * y1y + vj[u*3+2] * y1z;

  // ---- ABCD contraction: 9 weight tiles (8x4 rows from wr2, 1 row from br2) --
  float A[8], B[8], C[4], D[12];
  #pragma unroll
  for (int i = 0; i < 8; ++i) { A[i] = 0.f; B[i] = 0.f; }
  #pragma unroll
  for (int i = 0; i < 4; ++i) C[i] = 0.f;
  #pragma unroll
  for (int i = 0; i < 12; ++i) D[i] = 0.f;

  const float* wbase = wr2 + (size_t)layer * 32 * 2304;

  for (int t = 0; t < 9; ++t) {
    const int c0 = t * 4;
    const int nr = (t < 8) ? 4 : 1;
    // stage tile: coalesced float4 vector loads -> LDS (VGPR round-trip)
    if (t < 8) {
      const float4* gsrc = (const float4*)(wbase + (size_t)c0 * 2304);
      #pragma unroll
      for (int i = 0; i < 9; ++i) {          // 9*256 = 2304 float4 = 4 rows
        const int idx = i * 256 + tid;
        ((float4*)sW)[idx] = gsrc[idx];
      }
    } else {
      const float4* gsrc = (const float4*)(br2 + (size_t)layer * 2304);
      #pragma unroll
      for (int i = 0; i < 3; ++i) {          // 576 float4 = 1 row
        const int idx = i * 256 + tid;
        if (idx < 576) ((float4*)sW)[idx] = gsrc[idx];
      }
    }
    __syncthreads();  // tile staged (also covers sH on t==0)

    for (int r = 0; r < nr; ++r) {
      const float hc = sH[lane * 33 + c0 + r];
      const float* row = sW + r * 2304;
      const float* w1 = row + wq8;            // W1: u*32 + w
      const float* w2 = row + 1024 + wq8;     // W2: u*32 + w
      const float* w3 = row + 1536 + wq4;     // W3: u*16 + w
      const float* w4 = row + 2048 + wq4;     // W4: u*16 + w
      #pragma unroll
      for (int u = 0; u < 32; ++u) {
        const float p = hc * sj[u];
        const float4 a0 = *(const float4*)(w1 + u * 32);
        const float4 a1 = *(const float4*)(w1 + u * 32 + 4);
        A[0] += p * a0.x; A[1] += p * a0.y; A[2] += p * a0.z; A[3] += p * a0.w;
        A[4] += p * a1.x; A[5] += p * a1.y; A[6] += p * a1.z; A[7] += p * a1.w;
        const float4 c4 = *(const float4*)(w3 + u * 16);
        C[0] += p * c4.x; C[1] += p * c4.y; C[2] += p * c4.z; C[3] += p * c4.w;
      }
      #pragma unroll
      for (int u = 0; u < 16; ++u) {
        const float pb = hc * vdot[u];
        const float4 b0 = *(const float4*)(w2 + u * 32);
        const float4 b1 = *(const float4*)(w2 + u * 32 + 4);
        B[0] += pb * b0.x; B[1] += pb * b0.y; B[2] += pb * b0.z; B[3] += pb * b0.w;
        B[4] += pb * b1.x; B[5] += pb * b1.y; B[6] += pb * b1.z; B[7] += pb * b1.w;
        const float va = hc * vj[u * 3 + 0];
        const float vb = hc * vj[u * 3 + 1];
        const float vk = hc * vj[u * 3 + 2];
        const float4 d4 = *(const float4*)(w4 + u * 16);
        D[0] += va * d4.x; D[1]  += vb * d4.x; D[2]  += vk * d4.x;
        D[3] += va * d4.y; D[4]  += vb * d4.y; D[5]  += vk * d4.y;
        D[6] += va * d4.z; D[7]  += vb * d4.z; D[8]  += vk * d4.z;
        D[9] += va * d4.w; D[10] += vb * d4.w; D[11] += vk * d4.w;
      }
    }
    __syncthreads();  // done reading sW before next stage overwrites it
  }

  // each wave writes its exclusive sAcc slots
  #pragma unroll
  for (int wi = 0; wi < 8; ++wi) sAcc[lane * 129 + wq8 + wi] = A[wi];
  #pragma unroll
  for (int wi = 0; wi < 8; ++wi) sAcc[lane * 129 + 32 + wq8 + wi] = B[wi];
  #pragma unroll
  for (int wi = 0; wi < 4; ++wi) sAcc[lane * 129 + 64 + wq4 + wi] = C[wi];
  #pragma unroll
  for (int j = 0; j < 12; ++j)  sAcc[lane * 129 + 80 + wq4 * 3 + j] = D[j];
  __syncthreads();  // full A..D visible

  // ---- pg phase (w-split) ----
  float ps[8], ps32[4];
  #pragma unroll
  for (int i = 0; i < 8; ++i) ps[i] = 0.f;
  #pragma unroll
  for (int i = 0; i < 4; ++i) ps32[i] = 0.f;
  {
    const float* Wp = wpgs + layer * 1536;
    #pragma unroll
    for (int u = 0; u < 32; ++u) {
      const float ms = A_SC_F * (y0 * sAcc[lane * 129 + u]
                               + INV_SQRT3_F * sAcc[lane * 129 + 32 + u]);
      #pragma unroll
      for (int jj = 0; jj < 8; ++jj) ps[jj]   += ms * Wp[u * 48 + wq8 + jj];
      #pragma unroll
      for (int wi = 0; wi < 4; ++wi) ps32[wi] += ms * Wp[u * 48 + 32 + wq4 + wi];
    }
  }
  float pv[12];
  #pragma unroll
  for (int i = 0; i < 12; ++i) pv[i] = 0.f;
  {
    const float* Wp = wpgv + layer * 256;
    #pragma unroll
    for (int u = 0; u < 16; ++u) {
      const float cu = sAcc[lane * 129 + 64 + u];
      const float m0 = A_SC_F * (cu * y1x + y0 * sAcc[lane * 129 + 80 + u * 3 + 0]);
      const float m1 = A_SC_F * (cu * y1y + y0 * sAcc[lane * 129 + 80 + u * 3 + 1]);
      const float m2 = A_SC_F * (cu * y1z + y0 * sAcc[lane * 129 + 80 + u * 3 + 2]);
      #pragma unroll
      for (int wi = 0; wi < 4; ++wi) {
        const float wv = Wp[u * 16 + wq4 + wi];
        pv[wi * 3 + 0] += m0 * wv;
        pv[wi * 3 + 1] += m1 * wv;
        pv[wi * 3 + 2] += m2 * wv;
      }
    }
  }
  __syncthreads();  // everyone done READING A..D; safe to overwrite with gates

  // gates into exclusive slots: gs 0..31, gv 32..79
  #pragma unroll
  for (int jj = 0; jj < 8; ++jj) {
    const float t = ps[jj] * INV_SQRT_S_F;
    sAcc[lane * 129 + wq8 + jj] = t / (1.0f + __expf(-t));       // silu
  }
  #pragma unroll
  for (int wi = 0; wi < 4; ++wi) {
    const float g = 1.0f / (1.0f + __expf(-ps32[wi] * INV_SQRT_S_F));  // sigmoid
    #pragma unroll
    for (int k = 0; k < 3; ++k)
      sAcc[lane * 129 + 32 + (wq4 + wi) * 3 + k] = g * pv[wi * 3 + k] * INV_SQRT_V_F;
  }
  __syncthreads();  // gates visible

  // ---- o = g @ Wlo (w-split), scatter with HW fp32 atomics ----
  float os[8];
  #pragma unroll
  for (int i = 0; i < 8; ++i) os[i] = 0.f;
  {
    const float* Wp = wlos + layer * 1024;
    #pragma unroll
    for (int u = 0; u < 32; ++u) {
      const float g = sAcc[lane * 129 + u];
      #pragma unroll
      for (int wi = 0; wi < 8; ++wi) os[wi] += g * Wp[u * 32 + wq8 + wi];
    }
  }
  float ov[12];
  #pragma unroll
  for (int i = 0; i < 12; ++i) ov[i] = 0.f;
  {
    const float* Wp = wlov + layer * 256;
    #pragma unroll
    for (int u = 0; u < 16; ++u) {
      const float g0 = sAcc[lane * 129 + 32 + u * 3 + 0];
      const float g1 = sAcc[lane * 129 + 32 + u * 3 + 1];
      const float g2 = sAcc[lane * 129 + 32 + u * 3 + 2];
      #pragma unroll
      for (int wi = 0; wi < 4; ++wi) {
        const float wv = Wp[u * 16 + wq4 + wi];
        ov[wi * 3 + 0] += g0 * wv;
        ov[wi * 3 + 1] += g1 * wv;
        ov[wi * 3 + 2] += g2 * wv;
      }
    }
  }
  if (valid) {
    float* sdst = sn + (size_t)dstn * 32 + wq8;
    #pragma unroll
    for (int wi = 0; wi < 8; ++wi) unsafeAtomicAdd(&sdst[wi], os[wi] * INV_SQRT_S_F);
    float* vdst = vn + (size_t)dstn * 48 + wq4 * 3;
    #pragma unroll
    for (int j = 0; j < 12; ++j) unsafeAtomicAdd(&vdst[j], ov[j] * INV_SQRT_V_F);
  }
}

// out[n,k] = coeffs[n] @ M  (rho @ dirs collapsed analytically) — FP32 OUTPUT
__global__ __launch_bounds__(256) void final_kernel(
    const float* __restrict__ s0, const float* __restrict__ v0,
    const float* __restrict__ wos, const float* __restrict__ wov,
    const float* __restrict__ wf, float* __restrict__ out, int N)
{
  int n = blockIdx.x * 256 + threadIdx.x;
  if (n >= N) return;
  float cs = 0.f;
  #pragma unroll
  for (int u = 0; u < 32; ++u) cs += s0[n * 32 + u] * wos[u];
  cs *= INV_SQRT_S_F;
  float cv0 = 0.f, cv1 = 0.f, cv2 = 0.f;
  #pragma unroll
  for (int u = 0; u < 16; ++u) {
    const float wv = wov[u];
    cv0 += v0[n * 48 + u * 3 + 0] * wv;
    cv1 += v0[n * 48 + u * 3 + 1] * wv;
    cv2 += v0[n * 48 + u * 3 + 2] * wv;
  }
  cv0 *= INV_SQRT_V_F; cv1 *= INV_SQRT_V_F; cv2 *= INV_SQRT_V_F;
  #pragma unroll
  for (int k = 0; k < 3; ++k) {
    out[n * 3 + k] = cs  * wf[OFF_M + k]
                   + cv0 * wf[OFF_M + 3 + k]
                   + cv1 * wf[OFF_M + 6 + k]
                   + cv2 * wf[OFF_M + 9 + k];
  }
}

extern "C" void kernel_launch(void* const* d_in, const int* in_sizes, int n_in,
                              void* d_out, int out_size, void* d_ws, size_t ws_size,
                              hipStream_t stream)
{
  (void)n_in; (void)out_size; (void)ws_size;
  const float* x    = (const float*)d_in[0];
  const int*   ei   = (const int*)d_in[1];
  const float* ed   = (const float*)d_in[2];
  const float* esh  = (const float*)d_in[3];
  const float* dirs = (const float*)d_in[4];
  const float* wins = (const float*)d_in[5];
  const float* winv = (const float*)d_in[6];
  const float* wscs = (const float*)d_in[7];
  const float* wscv = (const float*)d_in[8];
  const float* wr1  = (const float*)d_in[9];
  const float* br1  = (const float*)d_in[10];
  const float* wr2  = (const float*)d_in[11];
  const float* br2  = (const float*)d_in[12];
  const float* wpgs = (const float*)d_in[13];
  const float* wpgv = (const float*)d_in[14];
  const float* wlos = (const float*)d_in[15];
  const float* wlov = (const float*)d_in[16];
  const float* wos  = (const float*)d_in[17];
  const float* wov  = (const float*)d_in[18];

  const int N = in_sizes[0] / 6;
  const int E = in_sizes[1] / 2;

  float* wf = (float*)d_ws;
  float* s0 = wf + OFF_NODE;
  float* v0 = s0 + (size_t)N * 32;
  float* s1 = v0 + (size_t)N * 48;
  float* v1 = s1 + (size_t)N * 32;

  const int nodeBlocks = (N * 80 + 255) / 256;
  const int edgeBlocks = (E + 63) / 64;
  const int finBlocks  = (N + 255) / 256;

  mmat_kernel<<<1, 64, 0, stream>>>(dirs, wf);
  node_init_kernel<<<nodeBlocks, 256, 0, stream>>>(x, wins, winv, s0, v0, N);

  // layer 0: s0/v0 -> s1/v1
  selfmix_kernel<<<nodeBlocks, 256, 0, stream>>>(s0, v0, s1, v1, wscs, wscv, 0, N);
  edge_kernel<<<edgeBlocks, 256, 0, stream>>>(ei, ed, esh, s0, v0, s1, v1,
      wr1, br1, wr2, br2, wpgs, wpgv, wlos, wlov, 0, E, N);
  // layer 1: s1/v1 -> s0/v0
  selfmix_kernel<<<nodeBlocks, 256, 0, stream>>>(s1, v1, s0, v0, wscs, wscv, 1, N);
  edge_kernel<<<edgeBlocks, 256, 0, stream>>>(ei, ed, esh, s1, v1, s0, v0,
      wr1, br1, wr2, br2, wpgs, wpgv, wlos, wlov, 1, E, N);

  final_kernel<<<finBlocks, 256, 0, stream>>>(s0, v0, wos, wov, wf,
      (float*)d_out, N);
}